// Round 1
// baseline (224.971 us; speedup 1.0000x reference)
//
#include <hip/hip_runtime.h>

#define B_   32
#define L_   256
#define T_   4096
#define YMAX 129   // y_max = W+1
#define NW   128   // n_words = y_max-1

// sub4(v) = ((v-1)//2 - 1)//2 with Python floor semantics (arith shift = floor div 2)
__device__ __forceinline__ int sub4i(int v) {
    return (((v - 1) >> 1) - 1) >> 1;
}

// ---------------------------------------------------------------------------
// Kernel 1: one block per batch. Computes, per row y in [0,YMAX):
//   token span [lo,hi), target frame span [tb,te), ylen; and the row-0
//   target tgt0[t] = max(0, 1 - coverage_count(t)) via diff-array + scan.
// Also zeroes d_out (harness poisons it with 0xAA before each timed launch).
// ---------------------------------------------------------------------------
__global__ __launch_bounds__(256) void setup_kernel(
    const int* __restrict__ wbeg, const int* __restrict__ wend,
    int* __restrict__ row_lo, int* __restrict__ row_hi,
    int* __restrict__ tgtb, int* __restrict__ tgte,
    int* __restrict__ ylen_ws, float* __restrict__ tgt0,
    float* __restrict__ out)
{
    const int b   = blockIdx.x;
    const int tid = threadIdx.x;          // 0..255, one per token position
    if (b == 0 && tid == 0) out[0] = 0.0f;

    __shared__ int s_bpos[NW], s_bval[NW], s_epos[NW], s_eval[NW];
    __shared__ int s_wc[8];               // per-wave valid counts (b:0..3, e:4..7)
    __shared__ int s_cov[T_];             // coverage diff/scan array (16 KiB)
    __shared__ int s_wsum[4];

    const int wb = wbeg[b * L_ + tid];
    const int we = wend[b * L_ + tid];
    const bool mb = (wb != -1);
    const bool me = (we != -1);
    const int lane = tid & 63;
    const int wv   = tid >> 6;

    unsigned long long balb = __ballot(mb);
    unsigned long long bale = __ballot(me);
    if (lane == 0) { s_wc[wv] = __popcll(balb); s_wc[4 + wv] = __popcll(bale); }
    __syncthreads();

    int offb = 0, offe = 0, nb = 0, ne = 0;
    for (int w = 0; w < 4; ++w) {
        int cb = s_wc[w], ce = s_wc[4 + w];
        if (w < wv) { offb += cb; offe += ce; }
        nb += cb; ne += ce;
    }
    const unsigned long long lmask = (1ull << lane) - 1ull;
    if (mb) {
        int r = offb + __popcll(balb & lmask);   // stable rank among valid begs
        if (r < NW) { s_bpos[r] = tid; s_bval[r] = sub4i(wb); }
    }
    if (me) {
        int r = offe + __popcll(bale & lmask);
        if (r < NW) { s_epos[r] = tid; s_eval[r] = sub4i(we); }
    }
    __syncthreads();

    if (tid == 0) ylen_ws[b] = nb + 1;

    if (tid < YMAX) {
        int lo, hi, tb, te;
        if (tid == 0) { lo = 0; hi = 1; tb = 0; te = 0; }   // row0 = e_0 (token 0)
        else {
            int k = tid - 1;                                 // word index
            if (k < nb) {
                lo = s_bpos[k] + 1;                          // tokens st+1 .. ed
                int epos = (k < ne) ? s_epos[k] : L_;        // pad = Ln
                hi = min(epos + 2, L_);                      // exclusive, clipped
                tb = s_bval[k];
                te = (k < ne) ? s_eval[k] : -1;              // sub4(-1) = -1 (empty)
            } else { lo = 0; hi = 0; tb = 0; te = 0; }       // invalid: masked anyway
        }
        int idx = b * YMAX + tid;
        row_lo[idx] = lo; row_hi[idx] = hi; tgtb[idx] = tb; tgte[idx] = te;
    }

    // ---- coverage count for tgt0: diff array + block prefix scan ----
    const int base = tid * 16;
    #pragma unroll
    for (int j = 0; j < 16; ++j) s_cov[base + j] = 0;
    __syncthreads();

    const int nwv = min(nb, NW);
    if (tid < nwv) {
        int bv = s_bval[tid];
        int ev = (tid < ne) ? s_eval[tid] : -1;
        int bvc = max(bv, 0);
        int evc = min(ev, T_);
        if (evc > bvc) {
            atomicAdd(&s_cov[bvc], 1);
            if (evc < T_) atomicAdd(&s_cov[evc], -1);
        }
    }
    __syncthreads();

    // sequential inclusive scan over this thread's 16 consecutive entries
    int run = 0;
    int loc[16];
    #pragma unroll
    for (int j = 0; j < 16; ++j) { run += s_cov[base + j]; loc[j] = run; }

    // wave-inclusive scan of thread totals
    int x = run;
    for (int d = 1; d < 64; d <<= 1) {
        int y = __shfl_up(x, d, 64);
        if (lane >= d) x += y;
    }
    if (lane == 63) s_wsum[wv] = x;
    __syncthreads();
    int woff = 0;
    for (int w = 0; w < wv; ++w) woff += s_wsum[w];
    const int excl = woff + x - run;     // exclusive prefix for this thread's chunk

    #pragma unroll
    for (int j = 0; j < 16; ++j) {
        int cov = excl + loc[j];
        tgt0[b * T_ + base + j] = fmaxf(0.0f, 1.0f - (float)cov);
    }
}

// ---------------------------------------------------------------------------
// Kernel 2: one block per (b, y). Each thread handles 4 consecutive frames
// per iteration (float4 loads), sums the row's token span, applies stable
// BCE-with-logits, block-reduces, atomicAdds scaled partial to out[0].
// ---------------------------------------------------------------------------
__global__ __launch_bounds__(256) void loss_kernel(
    const float* __restrict__ tse, const int* __restrict__ enc_len,
    const int* __restrict__ row_lo, const int* __restrict__ row_hi,
    const int* __restrict__ tgtb, const int* __restrict__ tgte,
    const int* __restrict__ ylen_ws, const float* __restrict__ tgt0,
    float* __restrict__ out)
{
    const int bid = blockIdx.x;
    const int b = bid / YMAX;
    const int y = bid - b * YMAX;
    if (y >= ylen_ws[b]) return;          // masked row: contributes 0
    const int n_t = enc_len[b];           // frames >= enc_len are masked: skip
    const int lo = row_lo[bid], hi = row_hi[bid];
    const int tb = tgtb[bid],  te = tgte[bid];
    const float* __restrict__ basep = tse + (size_t)b * (L_ * T_);
    const float* __restrict__ t0p   = tgt0 + b * T_;
    const int tid = threadIdx.x;

    float sum = 0.0f;
    for (int t0 = tid * 4; t0 < n_t; t0 += 1024) {
        // safe: t0 multiple of 4 and t0 < n_t <= T_ => t0+3 <= T_-1
        float4 x4 = make_float4(0.f, 0.f, 0.f, 0.f);
        for (int l = lo; l < hi; ++l) {
            const float4 v = *reinterpret_cast<const float4*>(basep + (size_t)l * T_ + t0);
            x4.x += v.x; x4.y += v.y; x4.z += v.z; x4.w += v.w;
        }
        const float xs[4] = {x4.x, x4.y, x4.z, x4.w};
        #pragma unroll
        for (int e = 0; e < 4; ++e) {
            const int t = t0 + e;
            if (t < n_t) {
                const float xv = xs[e];
                float tg;
                if (y == 0) tg = t0p[t];
                else        tg = (t >= tb && t < te) ? 1.0f : 0.0f;
                // max(x,0) - x*tgt + log1p(exp(-|x|)); |x| small so 1+exp is exact enough
                sum += fmaxf(xv, 0.0f) - xv * tg + __logf(1.0f + __expf(-fabsf(xv)));
            }
        }
    }

    // block reduction: wave shuffle + LDS
    const int lane = tid & 63;
    const int wv   = tid >> 6;
    for (int d = 32; d > 0; d >>= 1) sum += __shfl_down(sum, d, 64);
    __shared__ float s_part[4];
    if (lane == 0) s_part[wv] = sum;
    __syncthreads();
    if (tid == 0) {
        const float tot = s_part[0] + s_part[1] + s_part[2] + s_part[3];
        const float inv_total = (float)(1.0 / ((double)B_ * (double)YMAX * (double)T_));
        atomicAdd(out, tot * inv_total);
    }
}

extern "C" void kernel_launch(void* const* d_in, const int* in_sizes, int n_in,
                              void* d_out, int out_size, void* d_ws, size_t ws_size,
                              hipStream_t stream)
{
    const float* tse  = (const float*)d_in[0];   // [B, L, T] f32
    const int*   wbeg = (const int*)  d_in[1];   // [B, L] i32
    const int*   wend = (const int*)  d_in[2];   // [B, L] i32
    const int*   enc  = (const int*)  d_in[3];   // [B] i32
    // d_in[4] = y_max (129) — hard-coded as YMAX

    int* ws      = (int*)d_ws;
    int* row_lo  = ws;
    int* row_hi  = row_lo + B_ * YMAX;
    int* tb      = row_hi + B_ * YMAX;
    int* te      = tb     + B_ * YMAX;
    int* ylen    = te     + B_ * YMAX;
    float* tgt0  = (float*)(ylen + B_);          // B*T floats
    float* outp  = (float*)d_out;

    setup_kernel<<<B_, 256, 0, stream>>>(wbeg, wend, row_lo, row_hi, tb, te,
                                         ylen, tgt0, outp);
    loss_kernel<<<B_ * YMAX, 256, 0, stream>>>(tse, enc, row_lo, row_hi, tb, te,
                                               ylen, tgt0, outp);
}

// Round 2
// 189.986 us; speedup vs baseline: 1.1841x; 1.1841x over previous
//
#include <hip/hip_runtime.h>

#define B_   32
#define L_   256
#define T_   4096
#define YMAX 129   // y_max = W+1
#define NW   128   // n_words = y_max-1
#define NROW (B_ * YMAX)

// sub4(v) = ((v-1)//2 - 1)//2 with Python floor semantics (arith shift = floor div 2)
__device__ __forceinline__ int sub4i(int v) {
    return (((v - 1) >> 1) - 1) >> 1;
}

// ---------------------------------------------------------------------------
// Kernel 1: one block per batch. Computes, per row y in [0,YMAX):
//   token span [lo,hi), target frame span [tb,te), ylen; and the row-0
//   target tgt0[t] = max(0, 1 - coverage_count(t)) via diff-array + scan.
// ---------------------------------------------------------------------------
__global__ __launch_bounds__(256) void setup_kernel(
    const int* __restrict__ wbeg, const int* __restrict__ wend,
    int* __restrict__ row_lo, int* __restrict__ row_hi,
    int* __restrict__ tgtb, int* __restrict__ tgte,
    int* __restrict__ ylen_ws, float* __restrict__ tgt0)
{
    const int b   = blockIdx.x;
    const int tid = threadIdx.x;          // 0..255, one per token position

    __shared__ int s_bpos[NW], s_bval[NW], s_epos[NW], s_eval[NW];
    __shared__ int s_wc[8];               // per-wave valid counts (b:0..3, e:4..7)
    __shared__ int s_cov[T_];             // coverage diff/scan array (16 KiB)
    __shared__ int s_wsum[4];

    const int wb = wbeg[b * L_ + tid];
    const int we = wend[b * L_ + tid];
    const bool mb = (wb != -1);
    const bool me = (we != -1);
    const int lane = tid & 63;
    const int wv   = tid >> 6;

    unsigned long long balb = __ballot(mb);
    unsigned long long bale = __ballot(me);
    if (lane == 0) { s_wc[wv] = __popcll(balb); s_wc[4 + wv] = __popcll(bale); }
    __syncthreads();

    int offb = 0, offe = 0, nb = 0, ne = 0;
    for (int w = 0; w < 4; ++w) {
        int cb = s_wc[w], ce = s_wc[4 + w];
        if (w < wv) { offb += cb; offe += ce; }
        nb += cb; ne += ce;
    }
    const unsigned long long lmask = (1ull << lane) - 1ull;
    if (mb) {
        int r = offb + __popcll(balb & lmask);   // stable rank among valid begs
        if (r < NW) { s_bpos[r] = tid; s_bval[r] = sub4i(wb); }
    }
    if (me) {
        int r = offe + __popcll(bale & lmask);
        if (r < NW) { s_epos[r] = tid; s_eval[r] = sub4i(we); }
    }
    __syncthreads();

    if (tid == 0) ylen_ws[b] = nb + 1;

    if (tid < YMAX) {
        int lo, hi, tb, te;
        if (tid == 0) { lo = 0; hi = 1; tb = 0; te = 0; }   // row0 = token 0
        else {
            int k = tid - 1;                                 // word index
            if (k < nb) {
                lo = s_bpos[k] + 1;                          // tokens st+1 .. ed
                int epos = (k < ne) ? s_epos[k] : L_;        // pad = Ln
                hi = min(epos + 2, L_);                      // exclusive, clipped
                tb = s_bval[k];
                te = (k < ne) ? s_eval[k] : -1;              // empty span
            } else { lo = 0; hi = 0; tb = 0; te = 0; }       // invalid: masked anyway
        }
        int idx = b * YMAX + tid;
        row_lo[idx] = lo; row_hi[idx] = hi; tgtb[idx] = tb; tgte[idx] = te;
    }

    // ---- coverage count for tgt0: diff array + block prefix scan ----
    const int base = tid * 16;
    #pragma unroll
    for (int j = 0; j < 16; ++j) s_cov[base + j] = 0;
    __syncthreads();

    const int nwv = min(nb, NW);
    if (tid < nwv) {
        int bv = s_bval[tid];
        int ev = (tid < ne) ? s_eval[tid] : -1;
        int bvc = max(bv, 0);
        int evc = min(ev, T_);
        if (evc > bvc) {
            atomicAdd(&s_cov[bvc], 1);
            if (evc < T_) atomicAdd(&s_cov[evc], -1);
        }
    }
    __syncthreads();

    // sequential inclusive scan over this thread's 16 consecutive entries
    int run = 0;
    int loc[16];
    #pragma unroll
    for (int j = 0; j < 16; ++j) { run += s_cov[base + j]; loc[j] = run; }

    // wave-inclusive scan of thread totals
    int x = run;
    for (int d = 1; d < 64; d <<= 1) {
        int y = __shfl_up(x, d, 64);
        if (lane >= d) x += y;
    }
    if (lane == 63) s_wsum[wv] = x;
    __syncthreads();
    int woff = 0;
    for (int w = 0; w < wv; ++w) woff += s_wsum[w];
    const int excl = woff + x - run;     // exclusive prefix for this thread's chunk

    #pragma unroll
    for (int j = 0; j < 16; ++j) {
        int cov = excl + loc[j];
        tgt0[b * T_ + base + j] = fmaxf(0.0f, 1.0f - (float)cov);
    }
}

// ---------------------------------------------------------------------------
// Kernel 2: one block per (b, y). Each thread handles 4 consecutive frames
// per iteration (float4 loads), sums the row's 1-2 token rows, applies stable
// BCE-with-logits, block-reduces, writes partial to partials[bid].
// NO contended atomics — per-block partials, reduced by kernel 3.
// ---------------------------------------------------------------------------
__global__ __launch_bounds__(256) void loss_kernel(
    const float* __restrict__ tse, const int* __restrict__ enc_len,
    const int* __restrict__ row_lo, const int* __restrict__ row_hi,
    const int* __restrict__ tgtb, const int* __restrict__ tgte,
    const int* __restrict__ ylen_ws, const float* __restrict__ tgt0,
    float* __restrict__ partials)
{
    const int bid = blockIdx.x;
    const int b = bid / YMAX;
    const int y = bid - b * YMAX;
    const int tid = threadIdx.x;

    if (y >= ylen_ws[b]) {                // masked row: partial is exactly 0
        if (tid == 0) partials[bid] = 0.0f;   // ws is 0xAA-poisoned: must write
        return;
    }
    const int n_t = enc_len[b];           // frames >= enc_len are masked: skip
    const int lo = row_lo[bid], hi = row_hi[bid];
    const int tb = tgtb[bid],  te = tgte[bid];
    const bool two = (hi - lo) > 1;
    const float* __restrict__ p0 = tse + (size_t)b * (L_ * T_) + (size_t)lo * T_;
    const float* __restrict__ p1 = two ? (p0 + T_) : p0;   // second row (or dup)
    const float w1 = two ? 1.0f : 0.0f;
    const float* __restrict__ t0p = tgt0 + b * T_;

    float sum = 0.0f;
    for (int t0 = tid * 4; t0 < n_t; t0 += 1024) {
        // safe: t0 multiple of 4 and t0 < n_t <= T_ => t0+3 <= T_-1
        const float4 a = *reinterpret_cast<const float4*>(p0 + t0);
        const float4 c = *reinterpret_cast<const float4*>(p1 + t0);
        float xs[4] = {fmaf(w1, c.x, a.x), fmaf(w1, c.y, a.y),
                       fmaf(w1, c.z, a.z), fmaf(w1, c.w, a.w)};
        #pragma unroll
        for (int e = 0; e < 4; ++e) {
            const int t = t0 + e;
            if (t < n_t) {
                const float xv = xs[e];
                float tg;
                if (y == 0) tg = t0p[t];
                else        tg = (t >= tb && t < te) ? 1.0f : 0.0f;
                sum += fmaxf(xv, 0.0f) - xv * tg + __logf(1.0f + __expf(-fabsf(xv)));
            }
        }
    }

    // block reduction: wave shuffle + LDS
    const int lane = tid & 63;
    const int wv   = tid >> 6;
    for (int d = 32; d > 0; d >>= 1) sum += __shfl_down(sum, d, 64);
    __shared__ float s_part[4];
    if (lane == 0) s_part[wv] = sum;
    __syncthreads();
    if (tid == 0)
        partials[bid] = s_part[0] + s_part[1] + s_part[2] + s_part[3];
}

// ---------------------------------------------------------------------------
// Kernel 3: single block reduces the 4128 partials, scales, writes out[0].
// ---------------------------------------------------------------------------
__global__ __launch_bounds__(256) void reduce_kernel(
    const float* __restrict__ partials, float* __restrict__ out)
{
    const int tid = threadIdx.x;
    float sum = 0.0f;
    for (int i = tid; i < NROW; i += 256) sum += partials[i];
    const int lane = tid & 63;
    const int wv   = tid >> 6;
    for (int d = 32; d > 0; d >>= 1) sum += __shfl_down(sum, d, 64);
    __shared__ float s_part[4];
    if (lane == 0) s_part[wv] = sum;
    __syncthreads();
    if (tid == 0) {
        const float tot = s_part[0] + s_part[1] + s_part[2] + s_part[3];
        const float inv_total = (float)(1.0 / ((double)B_ * (double)YMAX * (double)T_));
        out[0] = tot * inv_total;
    }
}

extern "C" void kernel_launch(void* const* d_in, const int* in_sizes, int n_in,
                              void* d_out, int out_size, void* d_ws, size_t ws_size,
                              hipStream_t stream)
{
    const float* tse  = (const float*)d_in[0];   // [B, L, T] f32
    const int*   wbeg = (const int*)  d_in[1];   // [B, L] i32
    const int*   wend = (const int*)  d_in[2];   // [B, L] i32
    const int*   enc  = (const int*)  d_in[3];   // [B] i32
    // d_in[4] = y_max (129) — hard-coded as YMAX

    int* ws        = (int*)d_ws;
    int* row_lo    = ws;
    int* row_hi    = row_lo + NROW;
    int* tb        = row_hi + NROW;
    int* te        = tb     + NROW;
    int* ylen      = te     + NROW;
    float* tgt0    = (float*)(ylen + B_);        // B*T floats
    float* partial = tgt0 + B_ * T_;             // NROW floats
    float* outp    = (float*)d_out;

    setup_kernel<<<B_, 256, 0, stream>>>(wbeg, wend, row_lo, row_hi, tb, te,
                                         ylen, tgt0);
    loss_kernel<<<NROW, 256, 0, stream>>>(tse, enc, row_lo, row_hi, tb, te,
                                          ylen, tgt0, partial);
    reduce_kernel<<<1, 256, 0, stream>>>(partial, outp);
}